// Round 5
// baseline (629.813 us; speedup 1.0000x reference)
//
#include <hip/hip_runtime.h>
#include <hip/hip_bf16.h>
#include <math.h>

typedef __bf16 bf16x8 __attribute__((ext_vector_type(8)));
typedef short  s16x8  __attribute__((ext_vector_type(8)));
typedef float  f32x16 __attribute__((ext_vector_type(16)));
typedef unsigned short u16;

// ---- sizes ----
#define NN 32
#define CC 256
#define HH 56
#define WW 56
#define HP 68            // padded spatial (6 halo each side)
#define XP2_BYTES 75759616ull            // 32*68*68*256*2
#define XP2_OFF 0ull
#define WT3_OFF 75759616ull              // 200*16384 B = 3276800
#define T1_OFF  79036416ull              // 32*256*56*4 = 1835008
#define T9_OFF  80871424ull              // 32*56*56*4

__device__ inline u16 f2bf(float f) {
    unsigned int u = __builtin_bit_cast(unsigned int, f);
    u = (u + 0x7fffu + ((u >> 16) & 1u)) >> 16;   // RNE
    return (u16)u;
}

__device__ inline void gl_lds16(const char* g, char* l) {
    __builtin_amdgcn_global_load_lds(
        (const __attribute__((address_space(1))) unsigned int*)g,
        (__attribute__((address_space(3))) unsigned int*)l, 16, 0, 0);
}

// ---- zero only the halo of xp2 (interior fully written by prep) ----
__global__ void zero_halo(u16* __restrict__ xp2) {
    const int total = NN * 1488 * 32;           // 16B chunks
    int i = blockIdx.x * blockDim.x + threadIdx.x;
    const int stride = gridDim.x * blockDim.x;
    uint4 z; z.x = z.y = z.z = z.w = 0u;
    for (; i < total; i += stride) {
        int chunk = i & 31;
        int pid = i >> 5;
        int n = pid / 1488;
        int hp = pid - n * 1488;
        int row, col;
        if (hp < 816) { int r = hp / 68; col = hp - r * 68; row = (r < 6) ? r : r + 56; }
        else { int hq = hp - 816; int rr = hq / 12; int c12 = hq - rr * 12;
               row = 6 + rr; col = (c12 < 6) ? c12 : c12 + 56; }
        *(uint4*)((char*)xp2 + ((((size_t)n * HP + row) * HP + col) * 512) + chunk * 16) = z;
    }
}

// ---- pack w7 -> wt3 in 32x32x16 MFMA fragment order ----
// per kn block of 16KB: [ks(2)][rb(8)][lane(64)][8 cin u16]
// c_out = rb*32 + (lane&31); cin-in-chunk = ks*16 + (lane>>5)*8 + j.
__global__ __launch_bounds__(256)
void pack_w(const float* __restrict__ w7, u16* __restrict__ wt3) {
    int idx = blockIdx.x * 256 + threadIdx.x;    // 256*6400 total
    int c_out = idx / 6400;
    int k = idx - c_out * 6400;
    int cin = k / 25;
    int tap = k - cin * 25;
    int kn = tap * 8 + (cin >> 5);
    int c5 = cin & 31;
    int ks = c5 >> 4, half = (c5 >> 3) & 1, j = c5 & 7;
    int lane = half * 32 + (c_out & 31);
    int rb = c_out >> 5;
    wt3[(size_t)kn * 8192 + ks * 4096 + rb * 512 + lane * 8 + j] = f2bf(w7[idx]);
}

// ---- fused prep: t1 (row max, ILP4) + t9 (softmax of einsum) + pack x ----
// Reads x[n,:,h,:] ONCE (the separate t169+pack_x streamed all of x twice).
// Structure = pack_x's proven g-loop (8.4KB LDS, full occupancy) with the
// t169 reductions grafted in where x values are already in registers.
__global__ __launch_bounds__(256)
void prep(const float* __restrict__ x, const float* __restrict__ w6,
          float* __restrict__ t1, float* __restrict__ t9,
          u16* __restrict__ xp2) {
    const int n = blockIdx.x / HH;
    const int h = blockIdx.x % HH;
    const int lane = threadIdx.x & 63;
    const int wid = threadIdx.x >> 6;
    const bool valid = lane < WW;
    const int wl = valid ? lane : (WW - 1);
    __shared__ u16 xbuf[64 * 66];       // stride 66 u16: conflict-spread
    __shared__ float sbuf[4 * 64];
    const float* xrow = x + ((size_t)(n * CC) * HH + h) * WW;
    u16* dst = xp2 + (((size_t)n * HP + h + 6) * HP + 6) * CC;
    float accw = 0.f;
    for (int g = 0; g < 4; ++g) {
        if (g) __syncthreads();         // prior writeout done before overwrite
        const int c0 = g * 64 + wid * 16;
#pragma unroll
        for (int r0 = 0; r0 < 16; r0 += 4) {
            float xv0 = xrow[(size_t)(c0 + r0 + 0) * (HH * WW) + wl];
            float xv1 = xrow[(size_t)(c0 + r0 + 1) * (HH * WW) + wl];
            float xv2 = xrow[(size_t)(c0 + r0 + 2) * (HH * WW) + wl];
            float xv3 = xrow[(size_t)(c0 + r0 + 3) * (HH * WW) + wl];
            if (valid) {
                xbuf[(wid * 16 + r0 + 0) * 66 + lane] = f2bf(xv0);
                xbuf[(wid * 16 + r0 + 1) * 66 + lane] = f2bf(xv1);
                xbuf[(wid * 16 + r0 + 2) * 66 + lane] = f2bf(xv2);
                xbuf[(wid * 16 + r0 + 3) * 66 + lane] = f2bf(xv3);
            }
            float m0 = valid ? xv0 : -INFINITY;
            float m1 = valid ? xv1 : -INFINITY;
            float m2 = valid ? xv2 : -INFINITY;
            float m3 = valid ? xv3 : -INFINITY;
#pragma unroll
            for (int off = 32; off > 0; off >>= 1) {
                m0 = fmaxf(m0, __shfl_xor(m0, off));
                m1 = fmaxf(m1, __shfl_xor(m1, off));
                m2 = fmaxf(m2, __shfl_xor(m2, off));
                m3 = fmaxf(m3, __shfl_xor(m3, off));
            }
            if (lane == 0) {
                t1[(size_t)(n * CC + c0 + r0 + 0) * HH + h] = m0;
                t1[(size_t)(n * CC + c0 + r0 + 1) * HH + h] = m1;
                t1[(size_t)(n * CC + c0 + r0 + 2) * HH + h] = m2;
                t1[(size_t)(n * CC + c0 + r0 + 3) * HH + h] = m3;
            }
            if (valid) {
                // tanh(relu(x)) = 1 - 2/(exp(2*relu(x))+1)
                float e0 = __expf(2.f * fmaxf(xv0, 0.f));
                float e1 = __expf(2.f * fmaxf(xv1, 0.f));
                float e2 = __expf(2.f * fmaxf(xv2, 0.f));
                float e3 = __expf(2.f * fmaxf(xv3, 0.f));
                accw += (1.f - 2.f * __builtin_amdgcn_rcpf(e0 + 1.f)) * w6[c0 + r0 + 0];
                accw += (1.f - 2.f * __builtin_amdgcn_rcpf(e1 + 1.f)) * w6[c0 + r0 + 1];
                accw += (1.f - 2.f * __builtin_amdgcn_rcpf(e2 + 1.f)) * w6[c0 + r0 + 2];
                accw += (1.f - 2.f * __builtin_amdgcn_rcpf(e3 + 1.f)) * w6[c0 + r0 + 3];
            }
        }
        __syncthreads();
        // writeout: 56 pos x 8 chunks of 8 u16 (coalesced 16B stores)
        for (int id = threadIdx.x; id < WW * 8; id += 256) {
            int p = id >> 3, ch8 = id & 7;
            s16x8 pk;
#pragma unroll
            for (int j = 0; j < 8; ++j)
                pk[j] = (short)xbuf[(ch8 * 8 + j) * 66 + p];
            *(s16x8*)(dst + (size_t)p * CC + g * 64 + ch8 * 8) = pk;
        }
    }
    sbuf[wid * 64 + lane] = accw;
    __syncthreads();
    if (wid == 0) {
        float s = sbuf[lane] + sbuf[64 + lane] + sbuf[128 + lane] + sbuf[192 + lane];
        float sm = valid ? s : -INFINITY;
        float mx = sm;
#pragma unroll
        for (int off = 32; off > 0; off >>= 1)
            mx = fmaxf(mx, __shfl_xor(mx, off));
        float e = valid ? expf(s - mx) : 0.f;
        float tot = e;
#pragma unroll
        for (int off = 32; off > 0; off >>= 1)
            tot += __shfl_xor(tot, off);
        if (valid) t9[((size_t)n * HH + h) * WW + lane] = e / tot;
    }
}

// ---- main: implicit GEMM, 256 couts x 256 flat-spatial per block, BK=32 ----
// 512 thr = 8 waves (2 cout-groups x 4 pos-groups), per-wave 128x64 output,
// 32x32x16 MFMA. Fragment-order LDS (every frag read = base + lane*16,
// conflict-free). One barrier per K-tile; counted vmcnt(8) keeps 2 tiles in
// flight; setprio around MFMA clusters. t-loop unrolled x4 so every LDS
// buffer index is a compile-time constant (kills per-tile address chains);
// full tile prefetch issued at tile top.
__global__ __launch_bounds__(512, 2)
void conv_main(const char* __restrict__ xp2b, const char* __restrict__ wt3b,
               const float* __restrict__ x, const float* __restrict__ t1,
               const float* __restrict__ t9, float* __restrict__ out) {
    extern __shared__ __align__(16) char smem[];   // 4 * 32768 = 128 KiB
    const int bid = blockIdx.x;
    const int tile = (bid & 7) * 49 + (bid >> 3);   // XCD-aware swizzle
    const int tid  = threadIdx.x;
    const int wid  = tid >> 6;
    const int lane = tid & 63;
    const int l31 = lane & 31;
    const int lhi = lane >> 5;        // 0/1: k-half within a 16-k step
    const int wr = wid >> 2;          // cout half: rows [wr*128, +128)
    const int wc = wid & 3;           // pos quarter: cols [wc*64, +64)

    // B staging: wave wid stages col-block cb=wid (32 positions), both ks.
    // LDS slot lane holds pos (cb*32 + l31), cin bytes [ks*32+lhi*16, +16).
    unsigned vb;
    {
        int p = tile * 256 + wid * 32 + l31;
        int n = p / (HH * WW);
        int rem = p - n * (HH * WW);
        int hh = rem / WW;
        int ww = rem - hh * WW;
        vb = ((((unsigned)n * HP + hh + 6) * HP) + ww + 6) * 512 + lhi * 16;
    }

    // tt may exceed 199 (tail dummies wrap; their buffers are never read)
    auto stageA = [&](int tt, int ks) {
        const int kn = (tt < 200) ? tt : (tt - 200);
        const unsigned o = ks * 8192 + wid * 1024 + lane * 16;
        char* d = smem + (size_t)(tt & 3) * 32768 + o;
        const char* g = wt3b + (size_t)kn * 16384 + o;
        gl_lds16(g, d);
    };
    auto stageB = [&](int tt, int ks) {
        const int kn = (tt < 200) ? tt : (tt - 200);
        const int tp = kn >> 3, ch = kn & 7;
        const char* gb = xp2b +
            (ptrdiff_t)((tp / 5) * 3 - 6) * (HP * 512) +
            (ptrdiff_t)((tp % 5) * 3 - 6) * 512 + ch * 64 + ks * 32 + vb;
        char* d = smem + (size_t)(tt & 3) * 32768 + 16384
                  + ks * 8192 + wid * 1024 + lane * 16;
        gl_lds16(gb, d);
    };

    f32x16 acc[4][2];
#pragma unroll
    for (int mi = 0; mi < 4; ++mi)
#pragma unroll
        for (int nb = 0; nb < 2; ++nb)
#pragma unroll
            for (int r = 0; r < 16; ++r)
                acc[mi][nb][r] = 0.f;

    // fragment read offsets (contiguous 1KB per wave -> conflict-free)
    const int aoff = wr * 4096 + lane * 16;                 // + ks*8192 + mi*1024
    const int boff = 16384 + wc * 2048 + lane * 16;         // + ks*8192 + nb*1024

    // prologue: stage tiles 0,1,2 (12 loads/thread); wait tile 0 landed
#pragma unroll
    for (int tt = 0; tt < 3; ++tt) {
        stageA(tt, 0); stageB(tt, 0);
        stageA(tt, 1); stageB(tt, 1);
    }
    asm volatile("s_waitcnt vmcnt(8)" ::: "memory");
    __builtin_amdgcn_s_barrier();

    for (int tb = 0; tb < 200; tb += 4) {
#pragma unroll
        for (int u = 0; u < 4; ++u) {
            const int t = tb + u;
            const char* bp = smem + (size_t)u * 32768;   // (t&3)==u: compile-time
            // full next-tile prefetch at tile top (dst buffer (u+3)&3)
            stageA(t + 3, 0); stageB(t + 3, 0);
            stageA(t + 3, 1); stageB(t + 3, 1);
            bf16x8 av[4], bv[2];
#pragma unroll
            for (int ks = 0; ks < 2; ++ks) {
#pragma unroll
                for (int nb = 0; nb < 2; ++nb)
                    bv[nb] = *(const bf16x8*)(const void*)(bp + boff + ks * 8192 + nb * 1024);
#pragma unroll
                for (int mi = 0; mi < 4; ++mi)
                    av[mi] = *(const bf16x8*)(const void*)(bp + aoff + ks * 8192 + mi * 1024);
                __builtin_amdgcn_s_setprio(1);
#pragma unroll
                for (int mi = 0; mi < 4; ++mi)
#pragma unroll
                    for (int nb = 0; nb < 2; ++nb)
                        acc[mi][nb] = __builtin_amdgcn_mfma_f32_32x32x16_bf16(
                            av[mi], bv[nb], acc[mi][nb], 0, 0, 0);
                __builtin_amdgcn_s_setprio(0);
            }
            // counted wait: tiles t+2, t+3 (8 gl_lds/thread) stay in flight;
            // guarantees tile t+1 fully landed before the barrier releases.
            asm volatile("s_waitcnt vmcnt(8)" ::: "memory");
            __builtin_amdgcn_s_barrier();
        }
    }

    // epilogue: out = t1 - (t9 * roll(x,2,h) + x * t7)
    // C/D map (m74/m101): col = lane&31, row = (r&3) + 8*(r>>2) + 4*(lane>>5)
#pragma unroll
    for (int nb = 0; nb < 2; ++nb) {
        const int p = tile * 256 + wc * 64 + nb * 32 + l31;
        const int n = p / (HH * WW);
        const int rem = p - n * (HH * WW);
        const int h = rem / WW;
        const int w = rem - h * WW;
        const float t9v = t9[((size_t)n * HH + h) * WW + w];
        const int hprev = (h >= 2) ? (h - 2) : (h + HH - 2);
#pragma unroll
        for (int mi = 0; mi < 4; ++mi) {
            const int c0 = wr * 128 + mi * 32 + 4 * lhi;
#pragma unroll
            for (int r = 0; r < 16; ++r) {
                const int c = c0 + (r & 3) + 8 * (r >> 2);
                const size_t rowi = (size_t)(n * CC + c) * HH;
                const float t1v = t1[rowi + h];
                const float xv = x[(rowi + h) * WW + w];
                const float xr = x[(rowi + hprev) * WW + w];
                out[(rowi + h) * WW + w] = t1v - (t9v * xr + xv * acc[mi][nb][r]);
            }
        }
    }
}

extern "C" void kernel_launch(void* const* d_in, const int* in_sizes, int n_in,
                              void* d_out, int out_size, void* d_ws, size_t ws_size,
                              hipStream_t stream) {
    const float* x  = (const float*)d_in[0];
    const float* w6 = (const float*)d_in[1];
    const float* w7 = (const float*)d_in[2];
    float* out = (float*)d_out;
    char* ws = (char*)d_ws;
    u16*   xp2 = (u16*)(ws + XP2_OFF);
    u16*   wt3 = (u16*)(ws + WT3_OFF);
    float* t1  = (float*)(ws + T1_OFF);
    float* t9  = (float*)(ws + T9_OFF);

    static bool lds_cfg_done = false;
    if (!lds_cfg_done) {
        (void)hipFuncSetAttribute((const void*)conv_main,
                                  hipFuncAttributeMaxDynamicSharedMemorySize,
                                  131072);
        lds_cfg_done = true;
    }

    zero_halo<<<dim3(1024), dim3(256), 0, stream>>>(xp2);
    pack_w<<<dim3(6400), dim3(256), 0, stream>>>(w7, wt3);
    prep<<<dim3(NN * HH), dim3(256), 0, stream>>>(x, w6, t1, t9, xp2);
    conv_main<<<dim3(392), dim3(512), 131072, stream>>>((const char*)xp2, (const char*)wt3,
                                                        x, t1, t9, out);
}

// Round 6
// 585.941 us; speedup vs baseline: 1.0749x; 1.0749x over previous
//
#include <hip/hip_runtime.h>
#include <hip/hip_bf16.h>
#include <math.h>

typedef __bf16 bf16x8 __attribute__((ext_vector_type(8)));
typedef short  s16x8  __attribute__((ext_vector_type(8)));
typedef short  s16x4  __attribute__((ext_vector_type(4)));
typedef float  f32x16 __attribute__((ext_vector_type(16)));
typedef unsigned short u16;

// ---- sizes ----
#define NN 32
#define CC 256
#define HH 56
#define WW 56
#define HP 68            // padded spatial (6 halo each side)
#define XP2_BYTES 75759616ull            // 32*68*68*256*2
#define XP2_OFF 0ull
#define WT3_OFF 75759616ull              // 200*16384 B = 3276800
#define T1_OFF  79036416ull              // 32*256*56*4 = 1835008
#define T9_OFF  80871424ull              // 32*56*56*4

__device__ inline u16 f2bf(float f) {
    unsigned int u = __builtin_bit_cast(unsigned int, f);
    u = (u + 0x7fffu + ((u >> 16) & 1u)) >> 16;   // RNE
    return (u16)u;
}

__device__ inline void gl_lds16(const char* g, char* l) {
    __builtin_amdgcn_global_load_lds(
        (const __attribute__((address_space(1))) unsigned int*)g,
        (__attribute__((address_space(3))) unsigned int*)l, 16, 0, 0);
}

// ---- zero only the halo of xp2 (interior fully written by prep) ----
__global__ void zero_halo(u16* __restrict__ xp2) {
    const int total = NN * 1488 * 32;           // 16B chunks
    int i = blockIdx.x * blockDim.x + threadIdx.x;
    const int stride = gridDim.x * blockDim.x;
    uint4 z; z.x = z.y = z.z = z.w = 0u;
    for (; i < total; i += stride) {
        int chunk = i & 31;
        int pid = i >> 5;
        int n = pid / 1488;
        int hp = pid - n * 1488;
        int row, col;
        if (hp < 816) { int r = hp / 68; col = hp - r * 68; row = (r < 6) ? r : r + 56; }
        else { int hq = hp - 816; int rr = hq / 12; int c12 = hq - rr * 12;
               row = 6 + rr; col = (c12 < 6) ? c12 : c12 + 56; }
        *(uint4*)((char*)xp2 + ((((size_t)n * HP + row) * HP + col) * 512) + chunk * 16) = z;
    }
}

// ---- pack w7 -> wt3 in 32x32x16 MFMA fragment order ----
// per kn block of 16KB: [ks(2)][rb(8)][lane(64)][8 cin u16]
// c_out = rb*32 + (lane&31); cin-in-chunk = ks*16 + (lane>>5)*8 + j.
__global__ __launch_bounds__(256)
void pack_w(const float* __restrict__ w7, u16* __restrict__ wt3) {
    int idx = blockIdx.x * 256 + threadIdx.x;    // 256*6400 total
    int c_out = idx / 6400;
    int k = idx - c_out * 6400;
    int cin = k / 25;
    int tap = k - cin * 25;
    int kn = tap * 8 + (cin >> 5);
    int c5 = cin & 31;
    int ks = c5 >> 4, half = (c5 >> 3) & 1, j = c5 & 7;
    int lane = half * 32 + (c_out & 31);
    int rb = c_out >> 5;
    wt3[(size_t)kn * 8192 + ks * 4096 + rb * 512 + lane * 8 + j] = f2bf(w7[idx]);
}

// ---- fused prep: t1 (row max) + t9 (softmax of einsum) + pack x ----
// VECTORIZED: each thread loads float4 along w (lane = g16(4 c-rows) x
// wq(14 w-quads) -> 896B per wave-instruction vs 224B in the scalar
// version). Row-max = f32 shfl reduce within the 16-lane group; einsum
// keeps 4 per-w partials per thread, reduced via a small LDS table; pack
// keeps the proven LDS-transpose + coalesced 16B writeout.
__global__ __launch_bounds__(256)
void prep(const float* __restrict__ x, const float* __restrict__ w6,
          float* __restrict__ t1, float* __restrict__ t9,
          u16* __restrict__ xp2) {
    const int n = blockIdx.x / HH;
    const int h = blockIdx.x % HH;
    const int tid = threadIdx.x;
    const int lane = tid & 63;
    const int wid = tid >> 6;
    const int g16 = lane >> 4;        // 0..3: c-subrow within wave
    const int wq  = lane & 15;        // w-quad, active if <14
    const bool act = wq < 14;
    __shared__ u16 xbuf[64 * 60];     // row stride 60 u16 = 120B (8B-aligned rows)
    __shared__ float sacc[16][56];    // [c-group][w] einsum partials
    const float* xrow = x + ((size_t)(n * CC) * HH + h) * WW;
    u16* dst = xp2 + (((size_t)n * HP + h + 6) * HP + 6) * CC;
    float a0 = 0.f, a1 = 0.f, a2 = 0.f, a3 = 0.f;   // per-w partials (w=wq*4+j)
    for (int g = 0; g < 4; ++g) {
        if (g) __syncthreads();       // prior writeout done before overwrite
#pragma unroll
        for (int it = 0; it < 4; ++it) {
            const int cl = wid * 16 + it * 4 + g16;   // c_local in [0,64)
            const int c  = g * 64 + cl;
            float4 v = make_float4(0.f, 0.f, 0.f, 0.f);
            if (act) v = *(const float4*)(xrow + (size_t)c * (HH * WW) + wq * 4);
            if (act) {
                s16x4 pk;
                pk[0] = (short)f2bf(v.x); pk[1] = (short)f2bf(v.y);
                pk[2] = (short)f2bf(v.z); pk[3] = (short)f2bf(v.w);
                *(s16x4*)(xbuf + cl * 60 + wq * 4) = pk;
            }
            float m = act ? fmaxf(fmaxf(v.x, v.y), fmaxf(v.z, v.w)) : -INFINITY;
#pragma unroll
            for (int off = 8; off > 0; off >>= 1)
                m = fmaxf(m, __shfl_xor(m, off));     // reduce within 16-group
            if (wq == 0) t1[(size_t)(n * CC + c) * HH + h] = m;
            if (act) {
                const float wc = w6[c];
                // tanh(relu(x)) = 1 - 2/(exp(2*relu(x))+1)
                a0 += wc * (1.f - 2.f * __builtin_amdgcn_rcpf(__expf(2.f * fmaxf(v.x, 0.f)) + 1.f));
                a1 += wc * (1.f - 2.f * __builtin_amdgcn_rcpf(__expf(2.f * fmaxf(v.y, 0.f)) + 1.f));
                a2 += wc * (1.f - 2.f * __builtin_amdgcn_rcpf(__expf(2.f * fmaxf(v.z, 0.f)) + 1.f));
                a3 += wc * (1.f - 2.f * __builtin_amdgcn_rcpf(__expf(2.f * fmaxf(v.w, 0.f)) + 1.f));
            }
        }
        __syncthreads();
        // writeout: 56 pos x 8 chunks of 8 u16 (coalesced 16B stores)
        for (int id = tid; id < WW * 8; id += 256) {
            int p = id >> 3, ch8 = id & 7;
            s16x8 pk;
#pragma unroll
            for (int j = 0; j < 8; ++j)
                pk[j] = (short)xbuf[(ch8 * 8 + j) * 60 + p];
            *(s16x8*)(dst + (size_t)p * CC + g * 64 + ch8 * 8) = pk;
        }
    }
    if (act) {
        float* sl = sacc[wid * 4 + g16];
        sl[wq * 4 + 0] = a0; sl[wq * 4 + 1] = a1;
        sl[wq * 4 + 2] = a2; sl[wq * 4 + 3] = a3;
    }
    __syncthreads();
    if (wid == 0) {
        const bool valid = lane < WW;
        float s = 0.f;
        if (valid) {
#pragma unroll
            for (int gi = 0; gi < 16; ++gi) s += sacc[gi][lane];
        }
        float sm = valid ? s : -INFINITY;
        float mx = sm;
#pragma unroll
        for (int off = 32; off > 0; off >>= 1)
            mx = fmaxf(mx, __shfl_xor(mx, off));
        float e = valid ? expf(s - mx) : 0.f;
        float tot = e;
#pragma unroll
        for (int off = 32; off > 0; off >>= 1)
            tot += __shfl_xor(tot, off);
        if (valid) t9[((size_t)n * HH + h) * WW + lane] = e / tot;
    }
}

// ---- main: implicit GEMM, 256 couts x 256 flat-spatial per block, BK=32 ----
// 512 thr = 8 waves (2 cout-groups x 4 pos-groups), per-wave 128x64 output,
// 32x32x16 MFMA. Fragment-order LDS (every frag read = base + lane*16,
// conflict-free). One barrier per K-tile; counted vmcnt(8) keeps 2 tiles in
// flight; setprio around MFMA clusters. (r4 structure verbatim — the r5
// unroll-4 + tile-top prefetch variant regressed 401->427 and is reverted.)
__global__ __launch_bounds__(512, 2)
void conv_main(const char* __restrict__ xp2b, const char* __restrict__ wt3b,
               const float* __restrict__ x, const float* __restrict__ t1,
               const float* __restrict__ t9, float* __restrict__ out) {
    extern __shared__ __align__(16) char smem[];   // 4 * 32768 = 128 KiB
    const int bid = blockIdx.x;
    const int tile = (bid & 7) * 49 + (bid >> 3);   // XCD-aware swizzle
    const int tid  = threadIdx.x;
    const int wid  = tid >> 6;
    const int lane = tid & 63;
    const int l31 = lane & 31;
    const int lhi = lane >> 5;        // 0/1: k-half within a 16-k step
    const int wr = wid >> 2;          // cout half: rows [wr*128, +128)
    const int wc = wid & 3;           // pos quarter: cols [wc*64, +64)

    // B staging: wave wid stages col-block cb=wid (32 positions), both ks.
    // LDS slot lane holds pos (cb*32 + l31), cin bytes [ks*32+lhi*16, +16).
    unsigned vb;
    {
        int p = tile * 256 + wid * 32 + l31;
        int n = p / (HH * WW);
        int rem = p - n * (HH * WW);
        int hh = rem / WW;
        int ww = rem - hh * WW;
        vb = ((((unsigned)n * HP + hh + 6) * HP) + ww + 6) * 512 + lhi * 16;
    }

    // tt may exceed 199 (tail dummies wrap; their buffers are never read)
    auto stageA = [&](int tt, int ks) {
        const int kn = (tt < 200) ? tt : (tt - 200);
        const unsigned o = ks * 8192 + wid * 1024 + lane * 16;
        char* d = smem + (size_t)(tt & 3) * 32768 + o;
        const char* g = wt3b + (size_t)kn * 16384 + o;
        gl_lds16(g, d);
    };
    auto stageB = [&](int tt, int ks) {
        const int kn = (tt < 200) ? tt : (tt - 200);
        const int tp = kn >> 3, ch = kn & 7;
        const char* gb = xp2b +
            (ptrdiff_t)((tp / 5) * 3 - 6) * (HP * 512) +
            (ptrdiff_t)((tp % 5) * 3 - 6) * 512 + ch * 64 + ks * 32 + vb;
        char* d = smem + (size_t)(tt & 3) * 32768 + 16384
                  + ks * 8192 + wid * 1024 + lane * 16;
        gl_lds16(gb, d);
    };

    f32x16 acc[4][2];
#pragma unroll
    for (int mi = 0; mi < 4; ++mi)
#pragma unroll
        for (int nb = 0; nb < 2; ++nb)
#pragma unroll
            for (int r = 0; r < 16; ++r)
                acc[mi][nb][r] = 0.f;

    // fragment read offsets (contiguous 1KB per wave -> conflict-free)
    const int aoff = wr * 4096 + lane * 16;                 // + ks*8192 + mi*1024
    const int boff = 16384 + wc * 2048 + lane * 16;         // + ks*8192 + nb*1024

    // prologue: stage tiles 0,1,2 (12 loads/thread); wait tile 0 landed
#pragma unroll
    for (int tt = 0; tt < 3; ++tt) {
        stageA(tt, 0); stageB(tt, 0);
        stageA(tt, 1); stageB(tt, 1);
    }
    asm volatile("s_waitcnt vmcnt(8)" ::: "memory");
    __builtin_amdgcn_s_barrier();

    for (int t = 0; t < 200; ++t) {
        const char* bp = smem + (size_t)(t & 3) * 32768;
        bf16x8 av[4], bv[2];

#pragma unroll
        for (int ks = 0; ks < 2; ++ks) {
            stageA(t + 3, ks); stageB(t + 3, ks);
#pragma unroll
            for (int nb = 0; nb < 2; ++nb)
                bv[nb] = *(const bf16x8*)(const void*)(bp + boff + ks * 8192 + nb * 1024);
#pragma unroll
            for (int mi = 0; mi < 4; ++mi)
                av[mi] = *(const bf16x8*)(const void*)(bp + aoff + ks * 8192 + mi * 1024);
            __builtin_amdgcn_s_setprio(1);
#pragma unroll
            for (int mi = 0; mi < 4; ++mi)
#pragma unroll
                for (int nb = 0; nb < 2; ++nb)
                    acc[mi][nb] = __builtin_amdgcn_mfma_f32_32x32x16_bf16(
                        av[mi], bv[nb], acc[mi][nb], 0, 0, 0);
            __builtin_amdgcn_s_setprio(0);
        }
        // counted wait: tiles t+2, t+3 (8 gl_lds/thread) stay in flight;
        // guarantees tile t+1 fully landed before the barrier releases.
        asm volatile("s_waitcnt vmcnt(8)" ::: "memory");
        __builtin_amdgcn_s_barrier();
    }

    // epilogue: out = t1 - (t9 * roll(x,2,h) + x * t7)
    // C/D map (m74/m101): col = lane&31, row = (r&3) + 8*(r>>2) + 4*(lane>>5)
#pragma unroll
    for (int nb = 0; nb < 2; ++nb) {
        const int p = tile * 256 + wc * 64 + nb * 32 + l31;
        const int n = p / (HH * WW);
        const int rem = p - n * (HH * WW);
        const int h = rem / WW;
        const int w = rem - h * WW;
        const float t9v = t9[((size_t)n * HH + h) * WW + w];
        const int hprev = (h >= 2) ? (h - 2) : (h + HH - 2);
#pragma unroll
        for (int mi = 0; mi < 4; ++mi) {
            const int c0 = wr * 128 + mi * 32 + 4 * lhi;
#pragma unroll
            for (int r = 0; r < 16; ++r) {
                const int c = c0 + (r & 3) + 8 * (r >> 2);
                const size_t rowi = (size_t)(n * CC + c) * HH;
                const float t1v = t1[rowi + h];
                const float xv = x[(rowi + h) * WW + w];
                const float xr = x[(rowi + hprev) * WW + w];
                out[(rowi + h) * WW + w] = t1v - (t9v * xr + xv * acc[mi][nb][r]);
            }
        }
    }
}

extern "C" void kernel_launch(void* const* d_in, const int* in_sizes, int n_in,
                              void* d_out, int out_size, void* d_ws, size_t ws_size,
                              hipStream_t stream) {
    const float* x  = (const float*)d_in[0];
    const float* w6 = (const float*)d_in[1];
    const float* w7 = (const float*)d_in[2];
    float* out = (float*)d_out;
    char* ws = (char*)d_ws;
    u16*   xp2 = (u16*)(ws + XP2_OFF);
    u16*   wt3 = (u16*)(ws + WT3_OFF);
    float* t1  = (float*)(ws + T1_OFF);
    float* t9  = (float*)(ws + T9_OFF);

    static bool lds_cfg_done = false;
    if (!lds_cfg_done) {
        (void)hipFuncSetAttribute((const void*)conv_main,
                                  hipFuncAttributeMaxDynamicSharedMemorySize,
                                  131072);
        lds_cfg_done = true;
    }

    zero_halo<<<dim3(1024), dim3(256), 0, stream>>>(xp2);
    pack_w<<<dim3(6400), dim3(256), 0, stream>>>(w7, wt3);
    prep<<<dim3(NN * HH), dim3(256), 0, stream>>>(x, w6, t1, t9, xp2);
    conv_main<<<dim3(392), dim3(512), 131072, stream>>>((const char*)xp2, (const char*)wt3,
                                                        x, t1, t9, out);
}